// Round 9
// baseline (109.337 us; speedup 1.0000x reference)
//
#include <hip/hip_runtime.h>

#define RANK 16
#define N 512
#define ROWS 256            // b-rows per block: block = (a, b-half)
#define PTLD 260            // padded leading dim (floats): 1040 B rows, 16B-aligned

typedef float vfloat4 __attribute__((ext_vector_type(4)));

__global__ __launch_bounds__(256) void parafac_kernel(
    const float* __restrict__ f0,
    const float* __restrict__ f1,
    const float* __restrict__ f2,
    float* __restrict__ out)
{
    __shared__ float pt[RANK][PTLD];     // k-major product table, 16.25 KB

    const int t    = threadIdx.x;
    const int wave = t >> 6;
    const int lane = t & 63;
    const int blk  = blockIdx.x;         // 1024 blocks
    const int a    = blk >> 1;
    const int b0   = (blk & 1) * ROWS;

    // ---- Stage pt[k][b'] = f0[k][a] * f1[k][b0+b'] for all 256 rows, ONCE ----
    // thread t: k = t>>4, covers b' = (t&15)*4 + j*64, j=0..3 (4 vfloat4)
    {
        const int sk   = t >> 4;
        const int sbi0 = (t & 15) * 4;
        const float s  = f0[sk * N + a];
#pragma unroll
        for (int j = 0; j < 4; ++j) {
            const int sbi = sbi0 + j * 64;
            const vfloat4 f1v = *reinterpret_cast<const vfloat4*>(&f1[sk * N + b0 + sbi]);
            *reinterpret_cast<vfloat4*>(&pt[sk][sbi]) = s * f1v;
        }
    }

    // ---- f2 fragment resident in registers: 16 x float4 (64 VGPRs) ----
    const int c4 = (wave & 1) * 256 + lane * 4;
    vfloat4 v[RANK];
#pragma unroll
    for (int k = 0; k < RANK; ++k)
        v[k] = *reinterpret_cast<const vfloat4*>(&f2[k * N + c4]);

    __syncthreads();   // the ONLY barrier

    // ---- Steady state: 32 quads per wave, R6's exact inner loop, no pauses ----
    const int rpar = wave >> 1;          // quad parity
    float* outb = out + ((size_t)a * N + b0) * N + c4;

#pragma unroll 2
    for (int i = 0; i < 32; ++i) {
        const int qb = (rpar + 2 * i) * 4;       // row-quad base, 0..252
        vfloat4 acc0 = (vfloat4)(0.f);
        vfloat4 acc1 = (vfloat4)(0.f);
        vfloat4 acc2 = (vfloat4)(0.f);
        vfloat4 acc3 = (vfloat4)(0.f);
#pragma unroll
        for (int k = 0; k < RANK; ++k) {
            const vfloat4 pk = *reinterpret_cast<const vfloat4*>(&pt[k][qb]); // broadcast
            const vfloat4 vk = v[k];
            acc0 += pk.x * vk;
            acc1 += pk.y * vk;
            acc2 += pk.z * vk;
            acc3 += pk.w * vk;
        }
        float* o = outb + (size_t)qb * N;
        *reinterpret_cast<vfloat4*>(o)         = acc0;
        *reinterpret_cast<vfloat4*>(o + N)     = acc1;
        *reinterpret_cast<vfloat4*>(o + 2 * N) = acc2;
        *reinterpret_cast<vfloat4*>(o + 3 * N) = acc3;
    }
}

extern "C" void kernel_launch(void* const* d_in, const int* in_sizes, int n_in,
                              void* d_out, int out_size, void* d_ws, size_t ws_size,
                              hipStream_t stream) {
    const float* f0 = (const float*)d_in[0];
    const float* f1 = (const float*)d_in[1];
    const float* f2 = (const float*)d_in[2];
    float* out = (float*)d_out;

    dim3 grid(N * 2);   // 1024 blocks: (a, b-half); 4 blocks/CU, 16 waves/CU
    dim3 block(256);
    parafac_kernel<<<grid, block, 0, stream>>>(f0, f1, f2, out);
}

// Round 10
// 107.340 us; speedup vs baseline: 1.0186x; 1.0186x over previous
//
#include <hip/hip_runtime.h>

#define RANK 16
#define N 512
#define PTLD 516            // padded row stride (floats)

typedef float vfloat4 __attribute__((ext_vector_type(4)));

__global__ __launch_bounds__(1024, 4) void parafac_kernel(
    const float* __restrict__ f0,
    const float* __restrict__ f1,
    const float* __restrict__ f2,
    float* __restrict__ out)
{
    __shared__ float pt[RANK][PTLD];     // full k-major product table: 33 KB

    const int t    = threadIdx.x;
    const int wave = t >> 6;             // 0..15
    const int lane = t & 63;
    const int a    = blockIdx.x;         // one 1 MB a-slice per block

    // ---- Stage pt[k][b] = f0[k][a] * f1[k][b] for all b, once ----
    // wave k stages row k: lane covers 8 consecutive floats (2 x vfloat4)
    {
        const int sk = t >> 6;           // == wave
        const int c0 = (t & 63) * 8;
        const float s = f0[sk * N + a];
        const vfloat4 u0 = *reinterpret_cast<const vfloat4*>(&f1[sk * N + c0]);
        const vfloat4 u1 = *reinterpret_cast<const vfloat4*>(&f1[sk * N + c0 + 4]);
        *reinterpret_cast<vfloat4*>(&pt[sk][c0])     = s * u0;
        *reinterpret_cast<vfloat4*>(&pt[sk][c0 + 4]) = s * u1;
    }

    // ---- f2 fragment in registers: 16 x float4 (64 VGPRs), c-half per wave ----
    const int c4 = (wave & 1) * 256 + lane * 4;
    vfloat4 v[RANK];
#pragma unroll
    for (int k = 0; k < RANK; ++k)
        v[k] = *reinterpret_cast<const vfloat4*>(&f2[k * N + c4]);

    __syncthreads();   // only barrier

    // ---- 16 iterations; per iteration the 16 waves tile rows [32i, 32i+32)
    //      (8 row-quads x 2 c-halves) -> dense 64 KB window, monotone sweep ----
    const int rq = (wave >> 1) * 4;      // this wave's quad offset in the window
    float* outa = out + (size_t)a * N * N + c4;

#pragma unroll 2
    for (int i = 0; i < 16; ++i) {
        const int qb = i * 32 + rq;      // quad base row
        vfloat4 acc0 = (vfloat4)(0.f);
        vfloat4 acc1 = (vfloat4)(0.f);
        vfloat4 acc2 = (vfloat4)(0.f);
        vfloat4 acc3 = (vfloat4)(0.f);
#pragma unroll
        for (int k = 0; k < RANK; ++k) {
            const vfloat4 pk = *reinterpret_cast<const vfloat4*>(&pt[k][qb]); // broadcast
            const vfloat4 vk = v[k];
            acc0 += pk.x * vk;
            acc1 += pk.y * vk;
            acc2 += pk.z * vk;
            acc3 += pk.w * vk;
        }
        float* o = outa + (size_t)qb * N;
        *reinterpret_cast<vfloat4*>(o)         = acc0;
        *reinterpret_cast<vfloat4*>(o + N)     = acc1;
        *reinterpret_cast<vfloat4*>(o + 2 * N) = acc2;
        *reinterpret_cast<vfloat4*>(o + 3 * N) = acc3;
    }
}

extern "C" void kernel_launch(void* const* d_in, const int* in_sizes, int n_in,
                              void* d_out, int out_size, void* d_ws, size_t ws_size,
                              hipStream_t stream) {
    const float* f0 = (const float*)d_in[0];
    const float* f1 = (const float*)d_in[1];
    const float* f2 = (const float*)d_in[2];
    float* out = (float*)d_out;

    dim3 grid(N);        // 512 blocks, 1 per CU resident -> 256 dense regions
    dim3 block(1024);    // 16 waves, 4 waves/SIMD
    parafac_kernel<<<grid, block, 0, stream>>>(f0, f1, f2, out);
}